// Round 11
// baseline (373.353 us; speedup 1.0000x reference)
//
#include <hip/hip_runtime.h>
#include <math.h>
#include <stdint.h>

typedef unsigned short u16;
typedef __attribute__((ext_vector_type(8))) _Float16 f16x8;
typedef __attribute__((ext_vector_type(4))) float f32x4;

constexpr int NN = 10000;      // nodes
constexpr int NE = 160000;     // edges
constexpr int DD = 512;        // = H*C
constexpr int NL = 2;
constexpr int MPAD = 10112;    // 79*128
constexpr int K2 = 512;        // plain fp16 GEMM
constexpr int NC = 2048;       // C row stride (q/k/v fp16 | out f32)
constexpr int GZ = 32;         // gram K-chunks
constexpr int NKT = K2 / 64;   // 8 K-steps (BK=64)
constexpr float SCALE = 0.08838834764831845f; // 1/sqrt(128)

// ---------------- workspace layout (byte offsets) ----------------
// C row (8192B): u16 [0,1536) = q|k|v fp16 | f32 cols [1536,2048) = out
constexpr size_t B_C   = 0;                                   // [10016][2048] f32 (gram partials alias)
constexpr size_t B_XT  = (size_t)10016 * NC * 4;              // 82,051,072
constexpr size_t B_SM  = B_XT + (size_t)262144 * 4;           // small float block
constexpr size_t B_A2  = B_SM + 32768;                        // [10112][512] f16
constexpr size_t B_B2T = B_A2 + (size_t)MPAD * K2 * 2;        // [2][2048][512] f16
constexpr size_t B_INT = B_B2T + (size_t)2 * NC * K2 * 2;     // int region
// small-region float offsets
constexpr size_t SM_CS = 0, SM_CQ = 512, SM_CA = 1024, SM_CB = 1536;
constexpr size_t SM_PMN = 2048, SM_PMX = 2304, SM_MM = 2560, SM_BIAS = 2688; // bias 2*2048
// int sub-offsets
constexpr size_t I_INDPTR = 0;        // NN+1
constexpr size_t I_CNT    = 10016;    // NN
constexpr size_t I_CUR    = 20032;    // NN
constexpr size_t I_SSRC   = 30048;    // NE
constexpr size_t I_SATTR  = 190048;   // NE floats

// ---------------- helpers ----------------
__device__ __forceinline__ u16 f2h(float v) {
    _Float16 h = (_Float16)v;
    union { _Float16 h; u16 u; } x; x.h = h;
    return x.u;
}
__device__ __forceinline__ float h2f(u16 b) {
    union { u16 u; _Float16 h; } y; y.u = b;
    return (float)y.h;
}
__device__ __forceinline__ void gload16(const u16* g, u16* l) {
    __builtin_amdgcn_global_load_lds(
        (const __attribute__((address_space(1))) void*)g,
        (__attribute__((address_space(3))) void*)l, 16, 0, 0);
}
__device__ __forceinline__ void tile_pair(int p, int& ti, int& tj) {
    ti = (p < 4) ? 0 : (p < 7) ? 1 : (p < 9) ? 2 : 3;
    tj = p - ((ti == 0) ? 0 : (ti == 1) ? 3 : (ti == 2) ? 5 : 6);
}

// ---------------- CSR build ----------------
__global__ void hist_kernel(const int* __restrict__ dst, int* __restrict__ cnt) {
    int e = blockIdx.x * 256 + threadIdx.x;
    if (e < NE) atomicAdd(&cnt[dst[e]], 1);
}

__global__ void scan_kernel(const int* __restrict__ cnt, int* __restrict__ indptr,
                            int* __restrict__ cur) {
    __shared__ int sh[1024];
    int tid = threadIdx.x;
    int carry = 0;
    for (int base = 0; base < NN; base += 1024) {
        int idx = base + tid;
        int v = (idx < NN) ? cnt[idx] : 0;
        sh[tid] = v;
        __syncthreads();
        #pragma unroll
        for (int off = 1; off < 1024; off <<= 1) {
            int t = (tid >= off) ? sh[tid - off] : 0;
            __syncthreads();
            sh[tid] += t;
            __syncthreads();
        }
        int incl = sh[tid];
        int excl = incl - v;
        if (idx < NN) { indptr[idx] = carry + excl; cur[idx] = carry + excl; }
        int total = sh[1023];
        __syncthreads();
        carry += total;
    }
    if (tid == 0) indptr[NN] = carry;
}

__global__ void scatter_kernel(const int* __restrict__ src, const int* __restrict__ dst,
                               const float* __restrict__ eattr, int* __restrict__ cur,
                               int* __restrict__ ssrc, float* __restrict__ sattr) {
    int e = blockIdx.x * 256 + threadIdx.x;
    if (e < NE) {
        int d = dst[e];
        int p = atomicAdd(&cur[d], 1);
        ssrc[p]  = src[e];
        sattr[p] = eattr[e];
    }
}

// ---------------- conversions ----------------
__global__ void convert_x_kernel(const float* __restrict__ x, u16* __restrict__ A2) {
    size_t idx = (size_t)blockIdx.x * 256 + threadIdx.x;  // over MPAD*512
    if (idx >= (size_t)MPAD * 512) return;
    int r = (int)(idx >> 9), c = (int)(idx & 511);
    float v = (r < NN) ? x[(size_t)r * 512 + c] : 0.f;
    A2[(size_t)r * K2 + c] = f2h(v);
}

// grid (8,8,8): (ktile, ntile, l*4+mat); block (64,4)
__global__ void convert_w_kernel(const float* __restrict__ Wq, const float* __restrict__ Wk,
                                 const float* __restrict__ Wv, const float* __restrict__ Ws,
                                 u16* __restrict__ B2T) {
    __shared__ float t[64][65];
    int bz = blockIdx.z; int l = bz >> 2, m = bz & 3;
    const float* W = (m == 0 ? Wq : m == 1 ? Wk : m == 2 ? Wv : Ws) + (size_t)l * 512 * 512;
    int k0 = blockIdx.x * 64, n0 = blockIdx.y * 64;
    int tx = threadIdx.x, ty = threadIdx.y;
    #pragma unroll
    for (int i = 0; i < 16; i++) {
        int kk = ty + 4 * i;
        t[kk][tx] = W[(size_t)(k0 + kk) * 512 + n0 + tx];
    }
    __syncthreads();
    u16* B = B2T + (size_t)l * NC * K2;
    #pragma unroll
    for (int i = 0; i < 16; i++) {
        int nn = ty + 4 * i;
        B[(size_t)(m * 512 + n0 + nn) * K2 + k0 + tx] = f2h(t[tx][nn]);
    }
}

__global__ void convert_b_kernel(const float* __restrict__ bq, const float* __restrict__ bk,
                                 const float* __restrict__ bv, const float* __restrict__ bs,
                                 float* __restrict__ biascat) {
    int idx = blockIdx.x * 256 + threadIdx.x;  // 2*2048
    if (idx >= 2 * NC) return;
    int l = idx >> 11, c = idx & 2047;
    int m = c >> 9, j = c & 511;
    const float* b = (m == 0 ? bq : m == 1 ? bk : m == 2 ? bv : bs);
    biascat[idx] = b[l * 512 + j];
}

// ---------------- MFMA GEMM: [q|k|v|s] = A2[MPAD][512] @ B2T^T + bias ----------------
// Proven 2-barrier structure, BK=64 (8 K-steps). q/k/v fp16 epilogue, s f32.
__global__ __launch_bounds__(256) void gemm_mfma(
    const u16* __restrict__ A2, const u16* __restrict__ B2T,
    const float* __restrict__ biasc, float* __restrict__ C)
{
    __shared__ u16 As[8192];  // [128][64]
    __shared__ u16 Bs[8192];  // [128 cols][64 k]
    int tid = threadIdx.x;
    int wave = tid >> 6, lane = tid & 63;
    int wr = wave >> 1, wc = wave & 1;

    int bid = blockIdx.x;
    int xcd = bid & 7, qq = bid >> 3;          // 158 per XCD = 79 M x 2 N
    int half = (qq >= 79) ? 1 : 0;
    int mb = qq - half * 79;
    int nb = xcd * 2 + half;
    int row0 = mb * 128, col0 = nb * 128;
    int mtype = nb >> 2;                       // 0=q,1=k,2=v (fp16), 3=s (f32)

    int l8 = lane >> 3;                // 0..7: staging row within 8-row group
    int kofs = (lane & 7) * 8;         // 0..56: staging k offset (elements)
    const u16* gA = A2  + (size_t)(row0 + wave * 32 + l8) * K2 + kofs;
    const u16* gB = B2T + (size_t)(col0 + wave * 32 + l8) * K2 + kofs;
    u16* lA = &As[wave * 2048];
    u16* lB = &Bs[wave * 2048];

    f32x4 acc[4][4];
    #pragma unroll
    for (int m = 0; m < 4; ++m)
        #pragma unroll
        for (int n = 0; n < 4; ++n) acc[m][n] = (f32x4){0.f, 0.f, 0.f, 0.f};

    int frow = lane & 15, fk = (lane >> 4) * 8;

    for (int kt = 0; kt < NKT; ++kt) {
        #pragma unroll
        for (int j = 0; j < 4; ++j) {
            gload16(gA + j * 8 * K2, lA + j * 512);
            gload16(gB + j * 8 * K2, lB + j * 512);
        }
        gA += 64; gB += 64;
        __syncthreads();
        #pragma unroll
        for (int kk = 0; kk < 2; ++kk) {
            f16x8 af[4], bfr[4];
            #pragma unroll
            for (int m = 0; m < 4; ++m)
                af[m] = *reinterpret_cast<const f16x8*>(
                    &As[(wr * 64 + m * 16 + frow) * 64 + kk * 32 + fk]);
            #pragma unroll
            for (int n = 0; n < 4; ++n)
                bfr[n] = *reinterpret_cast<const f16x8*>(
                    &Bs[(wc * 64 + n * 16 + frow) * 64 + kk * 32 + fk]);
            #pragma unroll
            for (int m = 0; m < 4; ++m)
                #pragma unroll
                for (int n = 0; n < 4; ++n)
                    acc[m][n] = __builtin_amdgcn_mfma_f32_16x16x32_f16(af[m], bfr[n], acc[m][n], 0, 0, 0);
        }
        __syncthreads();
    }

    u16* KV = (u16*)C;   // q/k/v fp16 at u16 index r*4096 + gc (gc in [0,1536))
    int rq = lane >> 4;
    #pragma unroll
    for (int n = 0; n < 4; ++n) {
        int gc = col0 + wc * 64 + n * 16 + frow;
        float bv = biasc[gc];
        #pragma unroll
        for (int m = 0; m < 4; ++m) {
            int gr0 = row0 + wr * 64 + m * 16 + rq * 4;
            #pragma unroll
            for (int r = 0; r < 4; ++r) {
                int gr = gr0 + r;
                if (gr < NN) {
                    float val = acc[m][n][r] + bv;
                    if (mtype == 3) C[(size_t)gr * NC + gc] = val;
                    else            KV[(size_t)gr * 4096 + gc] = f2h(val);
                }
            }
        }
    }
}

// ---------------- per-node attention aggregate (online softmax, 2-deep prefetch) ----------------
__global__ __launch_bounds__(256) void agg_kernel(
    float* __restrict__ C, const float* __restrict__ Wel,
    const int* __restrict__ indptr, const int* __restrict__ ssrc,
    const float* __restrict__ sattr)
{
    int wid  = threadIdx.x >> 6;
    int lane = threadIdx.x & 63;
    int n = blockIdx.x * 4 + wid;
    if (n >= NN) return;
    int base = lane * 8;
    const u16* KV = (const u16*)C;

    union { uint4 u; u16 h[8]; } qr;
    qr.u = *(const uint4*)(KV + (size_t)n * 4096 + base);
    float qv[8];
    #pragma unroll
    for (int j = 0; j < 8; j++) qv[j] = h2f(qr.h[j]);
    float we[8];
    #pragma unroll
    for (int j = 0; j < 8; j++) we[j] = Wel[base + j];

    float t = 0.f;
    #pragma unroll
    for (int j = 0; j < 8; j++) t = fmaf(qv[j], we[j], t);
    #pragma unroll
    for (int m = 1; m < 16; m <<= 1) t += __shfl_xor(t, m, 64);
    float qWe = t;

    float mrun = -1e30f, msum = 0.f, cattr = 0.f;
    float acc[8] = {0.f,0.f,0.f,0.f,0.f,0.f,0.f,0.f};
    int p0 = indptr[n], p1 = indptr[n + 1];

    auto consume = [&](uint4 ku, uint4 vu, float at) {
        union { uint4 u; u16 h[8]; } kr, vr;
        kr.u = ku; vr.u = vu;
        float d = 0.f;
        #pragma unroll
        for (int j = 0; j < 8; j++) d = fmaf(qv[j], h2f(kr.h[j]), d);
        #pragma unroll
        for (int m = 1; m < 16; m <<= 1) d += __shfl_xor(d, m, 64);
        float logit = (d + at * qWe) * SCALE;
        float mnew = fmaxf(mrun, logit);
        float r = __expf(mrun - mnew);
        float a = __expf(logit - mnew);
        msum  = msum  * r + a;
        cattr = cattr * r + a * at;
        #pragma unroll
        for (int j = 0; j < 8; j++) acc[j] = acc[j] * r + a * h2f(vr.h[j]);
        mrun = mnew;
    };

    uint4 ka = {0,0,0,0}, va = {0,0,0,0}, kb = {0,0,0,0}, vb = {0,0,0,0};
    float ata = 0.f, atb = 0.f;
    if (p0 < p1) {
        int s = ssrc[p0]; ata = sattr[p0];
        ka = *(const uint4*)(KV + (size_t)s * 4096 + 512 + base);
        va = *(const uint4*)(KV + (size_t)s * 4096 + 1024 + base);
    }
    if (p0 + 1 < p1) {
        int s = ssrc[p0 + 1]; atb = sattr[p0 + 1];
        kb = *(const uint4*)(KV + (size_t)s * 4096 + 512 + base);
        vb = *(const uint4*)(KV + (size_t)s * 4096 + 1024 + base);
    }
    int p = p0;
    for (; p + 1 < p1; p += 2) {
        uint4 kc = ka, vc = va; float atc = ata;
        if (p + 2 < p1) {
            int s = ssrc[p + 2]; ata = sattr[p + 2];
            ka = *(const uint4*)(KV + (size_t)s * 4096 + 512 + base);
            va = *(const uint4*)(KV + (size_t)s * 4096 + 1024 + base);
        }
        consume(kc, vc, atc);
        kc = kb; vc = vb; atc = atb;
        if (p + 3 < p1) {
            int s = ssrc[p + 3]; atb = sattr[p + 3];
            kb = *(const uint4*)(KV + (size_t)s * 4096 + 512 + base);
            vb = *(const uint4*)(KV + (size_t)s * 4096 + 1024 + base);
        }
        consume(kc, vc, atc);
    }
    if (p < p1) consume(ka, va, ata);

    float inv = 1.f / (msum + 1e-16f);
    float* op = C + (size_t)n * NC + 1536 + base;
    float4 o0 = *(float4*)op, o1 = *(float4*)(op + 4);
    float ov[8] = {o0.x,o0.y,o0.z,o0.w,o1.x,o1.y,o1.z,o1.w};
    #pragma unroll
    for (int j = 0; j < 8; j++) ov[j] += (acc[j] + cattr * we[j]) * inv;
    *(float4*)op       = make_float4(ov[0], ov[1], ov[2], ov[3]);
    *(float4*)(op + 4) = make_float4(ov[4], ov[5], ov[6], ov[7]);
}

// ---------------- GraphNorm ----------------
__global__ void colstat_kernel(const float* __restrict__ C,
                               float* __restrict__ cs, float* __restrict__ cq) {
    int c = threadIdx.x; // 0..255
    int r0 = blockIdx.x * 125;
    float s0 = 0, s1 = 0, q0 = 0, q1 = 0;
    for (int r = r0; r < r0 + 125; ++r) {
        float v0 = C[(size_t)r * NC + 1536 + c];
        float v1 = C[(size_t)r * NC + 1536 + c + 256];
        s0 += v0; q0 += v0 * v0;
        s1 += v1; q1 += v1 * v1;
    }
    atomicAdd(&cs[c], s0);       atomicAdd(&cq[c], q0);
    atomicAdd(&cs[c + 256], s1); atomicAdd(&cq[c + 256], q1);
}

__global__ void coef_kernel(const float* __restrict__ cs, const float* __restrict__ cq,
                            const float* __restrict__ gnw, const float* __restrict__ gnb,
                            const float* __restrict__ gnm,
                            float* __restrict__ Aa, float* __restrict__ Bb) {
    int c = blockIdx.x * 256 + threadIdx.x;
    if (c >= DD) return;
    float mean = cs[c] * (1.f / NN);
    float ex2  = cq[c] * (1.f / NN);
    float ms = gnm[c];
    float var = ex2 - (2.f * ms - ms * ms) * mean * mean;
    float A = gnw[c] * rsqrtf(var + 1e-5f);
    Aa[c] = A;
    Bb[c] = gnb[c] - A * ms * mean;
}

// norm + relu + write fp16 into A2 for the next GEMM / gram
__global__ void normrelu_kernel(const float* __restrict__ C, const float* __restrict__ Aa,
                                const float* __restrict__ Bb, u16* __restrict__ A2) {
    for (size_t idx = (size_t)blockIdx.x * 256 + threadIdx.x; idx < (size_t)NN * 512;
         idx += (size_t)2048 * 256) {
        int r = (int)(idx >> 9), c = (int)(idx & 511);
        float v = fmaxf(fmaf(Aa[c], C[(size_t)r * NC + 1536 + c], Bb[c]), 0.f);
        A2[(size_t)r * K2 + c] = f2h(v);
    }
}

// ---------------- gram via MFMA (fp16) ----------------
__global__ __launch_bounds__(256) void gram_part_kernel(const u16* __restrict__ A2,
                                                        float* __restrict__ part) {
    __shared__ u16 LA[128][40], LB[128][40];   // [col][node], 80B rows: conflict-free
    int b = blockIdx.x;
    int p = b >> 5, z = b & (GZ - 1);
    int ti, tj; tile_pair(p, ti, tj);
    int i0c = ti * 128, j0c = tj * 128;
    int st0 = (z * 316) / GZ, st1 = ((z + 1) * 316) / GZ;

    int t = threadIdx.x;
    int c = t & 127, nb = t >> 7;              // staging: col c, node-halves nb
    int wave = t >> 6, lane = t & 63;
    int wr = wave >> 1, wc = wave & 1;
    int frow = lane & 15, fk = (lane >> 4) * 8, rq = lane >> 4;

    f32x4 acc[4][4];
    #pragma unroll
    for (int m = 0; m < 4; ++m)
        #pragma unroll
        for (int n = 0; n < 4; ++n) acc[m][n] = (f32x4){0.f, 0.f, 0.f, 0.f};

    for (int st = st0; st < st1; ++st) {
        int node0 = st * 32 + nb * 16;
        uint4 bufA4[2], bufB4[2];
        u16* ba = (u16*)bufA4; u16* bb = (u16*)bufB4;
        #pragma unroll
        for (int i = 0; i < 16; i++) {
            const u16* rp = A2 + (size_t)(node0 + i) * K2;
            ba[i] = rp[i0c + c];
            bb[i] = rp[j0c + c];
        }
        __syncthreads();
        *(uint4*)&LA[c][nb * 16]     = bufA4[0];
        *(uint4*)&LA[c][nb * 16 + 8] = bufA4[1];
        *(uint4*)&LB[c][nb * 16]     = bufB4[0];
        *(uint4*)&LB[c][nb * 16 + 8] = bufB4[1];
        __syncthreads();
        f16x8 af[4], bfr[4];
        #pragma unroll
        for (int m = 0; m < 4; ++m)
            af[m] = *reinterpret_cast<const f16x8*>(&LA[wr * 64 + m * 16 + frow][fk]);
        #pragma unroll
        for (int n = 0; n < 4; ++n)
            bfr[n] = *reinterpret_cast<const f16x8*>(&LB[wc * 64 + n * 16 + frow][fk]);
        #pragma unroll
        for (int m = 0; m < 4; ++m)
            #pragma unroll
            for (int n = 0; n < 4; ++n)
                acc[m][n] = __builtin_amdgcn_mfma_f32_16x16x32_f16(af[m], bfr[n], acc[m][n], 0, 0, 0);
    }

    float* pp = part + ((size_t)b << 14);      // b = p*GZ+z
    #pragma unroll
    for (int m = 0; m < 4; ++m) {
        int li0 = wr * 64 + m * 16 + rq * 4;
        #pragma unroll
        for (int n = 0; n < 4; ++n) {
            int lj = wc * 64 + n * 16 + frow;
            #pragma unroll
            for (int r = 0; r < 4; ++r)
                pp[(li0 + r) * 128 + lj] = acc[m][n][r];
        }
    }
}

// reduce GZ partials per cell -> xt, fused per-block min/max partials
__global__ __launch_bounds__(256) void gram_reduce_kernel(const float* __restrict__ part,
                                                          float* __restrict__ xt,
                                                          float* __restrict__ pmn,
                                                          float* __restrict__ pmx) {
    __shared__ float smn[256], smx[256];
    int tid = threadIdx.x;
    int g = blockIdx.x * 1024 + tid * 4;       // 160 blocks * 1024 = 163840 cells
    int p = g >> 14, idx = g & 16383;
    const float* bp = part + ((size_t)p * GZ << 14) + idx;
    float4 s = make_float4(0.f, 0.f, 0.f, 0.f);
    #pragma unroll
    for (int z = 0; z < GZ; ++z) {
        float4 v = *(const float4*)(bp + (size_t)z * 16384);
        s.x += v.x; s.y += v.y; s.z += v.z; s.w += v.w;
    }
    int ti, tj; tile_pair(p, ti, tj);
    int li = idx >> 7, lj = idx & 127;
    *(float4*)&xt[(size_t)(ti * 128 + li) * DD + tj * 128 + lj] = s;
    float mn = fminf(fminf(s.x, s.y), fminf(s.z, s.w));
    float mx = fmaxf(fmaxf(s.x, s.y), fmaxf(s.z, s.w));
    smn[tid] = mn; smx[tid] = mx;
    __syncthreads();
    for (int st = 128; st > 0; st >>= 1) {
        if (tid < st) {
            smn[tid] = fminf(smn[tid], smn[tid + st]);
            smx[tid] = fmaxf(smx[tid], smx[tid + st]);
        }
        __syncthreads();
    }
    if (tid == 0) { pmn[blockIdx.x] = smn[0]; pmx[blockIdx.x] = smx[0]; }
}

__global__ void minmax2_kernel(const float* __restrict__ pmn, const float* __restrict__ pmx,
                               float* __restrict__ mm) {
    __shared__ float smn[256], smx[256];
    int tid = threadIdx.x;
    smn[tid] = (tid < 160) ? pmn[tid] : 1e30f;
    smx[tid] = (tid < 160) ? pmx[tid] : -1e30f;
    __syncthreads();
    for (int s = 128; s > 0; s >>= 1) {
        if (tid < s) { smn[tid] = fminf(smn[tid], smn[tid + s]); smx[tid] = fmaxf(smx[tid], smx[tid + s]); }
        __syncthreads();
    }
    if (tid == 0) { mm[0] = smn[0]; mm[1] = smx[0]; }
}

__global__ void final_kernel(const float* __restrict__ xt, const float* __restrict__ mm,
                             float* __restrict__ outp) {
    int idx = blockIdx.x * 256 + threadIdx.x;
    if (idx >= 262144) return;
    int i = idx >> 9, j = idx & 511;
    if (j <= i) return;
    float mn = mm[0], mx = mm[1];
    float v = (xt[idx] - mn) / (mx - mn + 1e-8f);
    int p = i * 511 - (i * (i - 1)) / 2 + (j - i - 1);
    outp[p] = v;
}

// ---------------- launch ----------------
extern "C" void kernel_launch(void* const* d_in, const int* in_sizes, int n_in,
                              void* d_out, int out_size, void* d_ws, size_t ws_size,
                              hipStream_t stream) {
    const float* x     = (const float*)d_in[0];
    const int*   ei    = (const int*)d_in[1];
    const float* eattr = (const float*)d_in[2];
    const float* Wq = (const float*)d_in[3];  const float* bq = (const float*)d_in[4];
    const float* Wk = (const float*)d_in[5];  const float* bk = (const float*)d_in[6];
    const float* Wv = (const float*)d_in[7];  const float* bv = (const float*)d_in[8];
    const float* We = (const float*)d_in[9];
    const float* Ws = (const float*)d_in[10]; const float* bs = (const float*)d_in[11];
    const float* gnw = (const float*)d_in[12];
    const float* gnb = (const float*)d_in[13];
    const float* gnm = (const float*)d_in[14];

    char*  wsb = (char*)d_ws;
    float* C    = (float*)(wsb + B_C);
    float* xt   = (float*)(wsb + B_XT);
    float* sm   = (float*)(wsb + B_SM);
    u16*   A2   = (u16*)(wsb + B_A2);
    u16*   B2T  = (u16*)(wsb + B_B2T);
    int*   wsI  = (int*)(wsb + B_INT);

    const int* src = ei;
    const int* dst = ei + NE;

    // conversions (once per call)
    convert_x_kernel<<<(MPAD * 512) / 256, 256, 0, stream>>>(x, A2);
    convert_w_kernel<<<dim3(8, 8, 8), dim3(64, 4), 0, stream>>>(Wq, Wk, Wv, Ws, B2T);
    convert_b_kernel<<<16, 256, 0, stream>>>(bq, bk, bv, bs, sm + SM_BIAS);

    // CSR by dst
    hipMemsetAsync(wsI + I_CNT, 0, NN * sizeof(int), stream);
    hist_kernel<<<(NE + 255) / 256, 256, 0, stream>>>(dst, wsI + I_CNT);
    scan_kernel<<<1, 1024, 0, stream>>>(wsI + I_CNT, wsI + I_INDPTR, wsI + I_CUR);
    scatter_kernel<<<(NE + 255) / 256, 256, 0, stream>>>(src, dst, eattr, wsI + I_CUR,
                                                         wsI + I_SSRC, (float*)(wsI + I_SATTR));

    for (int l = 0; l < NL; ++l) {
        gemm_mfma<<<1264, 256, 0, stream>>>(A2, B2T + (size_t)l * NC * K2,
                                            sm + SM_BIAS + (size_t)l * NC, C);

        agg_kernel<<<2500, 256, 0, stream>>>(C, We + (size_t)l * DD,
                                             wsI + I_INDPTR, wsI + I_SSRC,
                                             (const float*)(wsI + I_SATTR));

        hipMemsetAsync(sm + SM_CS, 0, 1024 * sizeof(float), stream);
        colstat_kernel<<<80, 256, 0, stream>>>(C, sm + SM_CS, sm + SM_CQ);
        coef_kernel<<<2, 256, 0, stream>>>(sm + SM_CS, sm + SM_CQ,
                                           gnw + (size_t)l * DD, gnb + (size_t)l * DD,
                                           gnm + (size_t)l * DD, sm + SM_CA, sm + SM_CB);
        normrelu_kernel<<<2048, 256, 0, stream>>>(C, sm + SM_CA, sm + SM_CB, A2);
    }

    // gram: partials (alias dead C buffer) -> reduce(+minmax) -> final
    float* part = C;
    gram_part_kernel<<<10 * GZ, 256, 0, stream>>>(A2, part);
    gram_reduce_kernel<<<160, 256, 0, stream>>>(part, xt, sm + SM_PMN, sm + SM_PMX);
    minmax2_kernel<<<1, 256, 0, stream>>>(sm + SM_PMN, sm + SM_PMX, sm + SM_MM);
    final_kernel<<<1024, 256, 0, stream>>>(xt, sm + SM_MM, (float*)d_out);
}

// Round 12
// 343.172 us; speedup vs baseline: 1.0879x; 1.0879x over previous
//
#include <hip/hip_runtime.h>
#include <math.h>
#include <stdint.h>

typedef unsigned short u16;
typedef __attribute__((ext_vector_type(8))) _Float16 f16x8;
typedef __attribute__((ext_vector_type(4))) float f32x4;

constexpr int NN = 10000;      // nodes
constexpr int NE = 160000;     // edges
constexpr int DD = 512;        // = H*C
constexpr int NL = 2;
constexpr int MPAD = 10112;    // 79*128
constexpr int K2 = 512;        // plain fp16 GEMM
constexpr int NC = 2048;       // C row stride (q f32 | kv fp16 alias | out f32)
constexpr int GZ = 32;         // gram K-chunks
constexpr int NKT = K2 / 32;   // 16 K-steps (BK=32, proven)
constexpr float SCALE = 0.08838834764831845f; // 1/sqrt(128)

// ---------------- workspace layout (byte offsets) ----------------
// C row (8192B): [0,2048)=q f32 | u16 idx [1024,2048) = k,v fp16 | f32 [1536,2048)=out
constexpr size_t B_C   = 0;                                   // [10016][2048] f32 (gram partials alias)
constexpr size_t B_XT  = (size_t)10016 * NC * 4;              // 82,051,072
constexpr size_t B_SM  = B_XT + (size_t)262144 * 4;           // small float block
constexpr size_t B_A2  = B_SM + 32768;                        // [10112][512] f16
constexpr size_t B_B2T = B_A2 + (size_t)MPAD * K2 * 2;        // [2][2048][512] f16
constexpr size_t B_INT = B_B2T + (size_t)2 * NC * K2 * 2;     // int region
// small-region float offsets
constexpr size_t SM_CS = 0, SM_CQ = 512, SM_CA = 1024, SM_CB = 1536;
constexpr size_t SM_PMN = 2048, SM_PMX = 2304, SM_MM = 2560, SM_BIAS = 2688; // bias 2*2048
// int sub-offsets
constexpr size_t I_INDPTR = 0;        // NN+1
constexpr size_t I_CNT    = 10016;    // NN
constexpr size_t I_CUR    = 20032;    // NN
constexpr size_t I_SSRC   = 30048;    // NE
constexpr size_t I_SATTR  = 190048;   // NE floats

// ---------------- helpers ----------------
__device__ __forceinline__ u16 f2h(float v) {
    _Float16 h = (_Float16)v;
    union { _Float16 h; u16 u; } x; x.h = h;
    return x.u;
}
__device__ __forceinline__ float h2f(u16 b) {
    union { u16 u; _Float16 h; } y; y.u = b;
    return (float)y.h;
}
__device__ __forceinline__ void gload16(const u16* g, u16* l) {
    __builtin_amdgcn_global_load_lds(
        (const __attribute__((address_space(1))) void*)g,
        (__attribute__((address_space(3))) void*)l, 16, 0, 0);
}
__device__ __forceinline__ void tile_pair(int p, int& ti, int& tj) {
    ti = (p < 4) ? 0 : (p < 7) ? 1 : (p < 9) ? 2 : 3;
    tj = p - ((ti == 0) ? 0 : (ti == 1) ? 3 : (ti == 2) ? 5 : 6);
}

// ---------------- CSR build ----------------
__global__ void hist_kernel(const int* __restrict__ dst, int* __restrict__ cnt) {
    int e = blockIdx.x * 256 + threadIdx.x;
    if (e < NE) atomicAdd(&cnt[dst[e]], 1);
}

__global__ void scan_kernel(const int* __restrict__ cnt, int* __restrict__ indptr,
                            int* __restrict__ cur) {
    __shared__ int sh[1024];
    int tid = threadIdx.x;
    int carry = 0;
    for (int base = 0; base < NN; base += 1024) {
        int idx = base + tid;
        int v = (idx < NN) ? cnt[idx] : 0;
        sh[tid] = v;
        __syncthreads();
        #pragma unroll
        for (int off = 1; off < 1024; off <<= 1) {
            int t = (tid >= off) ? sh[tid - off] : 0;
            __syncthreads();
            sh[tid] += t;
            __syncthreads();
        }
        int incl = sh[tid];
        int excl = incl - v;
        if (idx < NN) { indptr[idx] = carry + excl; cur[idx] = carry + excl; }
        int total = sh[1023];
        __syncthreads();
        carry += total;
    }
    if (tid == 0) indptr[NN] = carry;
}

__global__ void scatter_kernel(const int* __restrict__ src, const int* __restrict__ dst,
                               const float* __restrict__ eattr, int* __restrict__ cur,
                               int* __restrict__ ssrc, float* __restrict__ sattr) {
    int e = blockIdx.x * 256 + threadIdx.x;
    if (e < NE) {
        int d = dst[e];
        int p = atomicAdd(&cur[d], 1);
        ssrc[p]  = src[e];
        sattr[p] = eattr[e];
    }
}

// ---------------- conversions ----------------
__global__ void convert_x_kernel(const float* __restrict__ x, u16* __restrict__ A2) {
    size_t idx = (size_t)blockIdx.x * 256 + threadIdx.x;  // over MPAD*512
    if (idx >= (size_t)MPAD * 512) return;
    int r = (int)(idx >> 9), c = (int)(idx & 511);
    float v = (r < NN) ? x[(size_t)r * 512 + c] : 0.f;
    A2[(size_t)r * K2 + c] = f2h(v);
}

// grid (8,8,8): (ktile, ntile, l*4+mat); block (64,4)
__global__ void convert_w_kernel(const float* __restrict__ Wq, const float* __restrict__ Wk,
                                 const float* __restrict__ Wv, const float* __restrict__ Ws,
                                 u16* __restrict__ B2T) {
    __shared__ float t[64][65];
    int bz = blockIdx.z; int l = bz >> 2, m = bz & 3;
    const float* W = (m == 0 ? Wq : m == 1 ? Wk : m == 2 ? Wv : Ws) + (size_t)l * 512 * 512;
    int k0 = blockIdx.x * 64, n0 = blockIdx.y * 64;
    int tx = threadIdx.x, ty = threadIdx.y;
    #pragma unroll
    for (int i = 0; i < 16; i++) {
        int kk = ty + 4 * i;
        t[kk][tx] = W[(size_t)(k0 + kk) * 512 + n0 + tx];
    }
    __syncthreads();
    u16* B = B2T + (size_t)l * NC * K2;
    #pragma unroll
    for (int i = 0; i < 16; i++) {
        int nn = ty + 4 * i;
        B[(size_t)(m * 512 + n0 + nn) * K2 + k0 + tx] = f2h(t[tx][nn]);
    }
}

__global__ void convert_b_kernel(const float* __restrict__ bq, const float* __restrict__ bk,
                                 const float* __restrict__ bv, const float* __restrict__ bs,
                                 float* __restrict__ biascat) {
    int idx = blockIdx.x * 256 + threadIdx.x;  // 2*2048
    if (idx >= 2 * NC) return;
    int l = idx >> 11, c = idx & 2047;
    int m = c >> 9, j = c & 511;
    const float* b = (m == 0 ? bq : m == 1 ? bk : m == 2 ? bv : bs);
    biascat[idx] = b[l * 512 + j];
}

// ---------------- MFMA GEMM: [q|k|v|s] = A2[MPAD][512] @ B2T^T + bias ----------------
// Round-10 winning structure: single LDS buffer, BK=32, 2 barriers/K-step.
__global__ __launch_bounds__(256) void gemm_mfma(
    const u16* __restrict__ A2, const u16* __restrict__ B2T,
    const float* __restrict__ biasc, float* __restrict__ C)
{
    __shared__ u16 As[4096];  // [128][32]
    __shared__ u16 Bs[4096];  // [128 cols][32 k]
    int tid = threadIdx.x;
    int wave = tid >> 6, lane = tid & 63;
    int wr = wave >> 1, wc = wave & 1;

    int bid = blockIdx.x;
    int xcd = bid & 7, qq = bid >> 3;          // 158 per XCD = 79 M x 2 N
    int half = (qq >= 79) ? 1 : 0;
    int mb = qq - half * 79;
    int nb = xcd * 2 + half;
    int row0 = mb * 128, col0 = nb * 128;
    int mtype = nb >> 2;                       // 0=q,1=k,2=v,3=s (block-uniform)

    int ar0 = tid >> 2;                // staging row within tile
    int ac0 = (tid & 3) * 8;           // staging k offset (elements)
    const u16* gA = A2  + (size_t)(row0 + ar0) * K2 + ac0;
    const u16* gB = B2T + (size_t)(col0 + ar0) * K2 + ac0;
    u16* lA = &As[wave * 512];
    u16* lB = &Bs[wave * 512];

    f32x4 acc[4][4];
    #pragma unroll
    for (int m = 0; m < 4; ++m)
        #pragma unroll
        for (int n = 0; n < 4; ++n) acc[m][n] = (f32x4){0.f, 0.f, 0.f, 0.f};

    int frow = lane & 15, fk = (lane >> 4) * 8;

    for (int kt = 0; kt < NKT; ++kt) {
        gload16(gA,             lA);
        gload16(gA + 64 * K2,   lA + 2048);
        gload16(gB,             lB);
        gload16(gB + 64 * K2,   lB + 2048);
        gA += 32; gB += 32;
        __syncthreads();
        f16x8 af[4], bfr[4];
        #pragma unroll
        for (int m = 0; m < 4; ++m)
            af[m] = *reinterpret_cast<const f16x8*>(&As[(wr * 64 + m * 16 + frow) * 32 + fk]);
        #pragma unroll
        for (int n = 0; n < 4; ++n)
            bfr[n] = *reinterpret_cast<const f16x8*>(&Bs[(wc * 64 + n * 16 + frow) * 32 + fk]);
        #pragma unroll
        for (int m = 0; m < 4; ++m)
            #pragma unroll
            for (int n = 0; n < 4; ++n)
                acc[m][n] = __builtin_amdgcn_mfma_f32_16x16x32_f16(af[m], bfr[n], acc[m][n], 0, 0, 0);
        __syncthreads();
    }

    u16* KV = (u16*)C;   // fp16 k/v live at u16 index r*4096 + 512 + gc  (gc in [512,1536))
    int rq = lane >> 4;
    #pragma unroll
    for (int n = 0; n < 4; ++n) {
        int gc = col0 + wc * 64 + n * 16 + frow;
        float bv = biasc[gc];
        #pragma unroll
        for (int m = 0; m < 4; ++m) {
            int gr0 = row0 + wr * 64 + m * 16 + rq * 4;
            #pragma unroll
            for (int r = 0; r < 4; ++r) {
                int gr = gr0 + r;
                if (gr < NN) {
                    float val = acc[m][n][r] + bv;
                    if (mtype == 0 || mtype == 3) C[(size_t)gr * NC + gc] = val;
                    else                          KV[(size_t)gr * 4096 + 512 + gc] = f2h(val);
                }
            }
        }
    }
}

// ---------------- per-node attention aggregate (online softmax, 2-deep prefetch) ----------------
__global__ __launch_bounds__(256) void agg_kernel(
    float* __restrict__ C, const float* __restrict__ Wel,
    const int* __restrict__ indptr, const int* __restrict__ ssrc,
    const float* __restrict__ sattr)
{
    int wid  = threadIdx.x >> 6;
    int lane = threadIdx.x & 63;
    int n = blockIdx.x * 4 + wid;
    if (n >= NN) return;
    int base = lane * 8;
    const u16* KV = (const u16*)C;

    const float4* qp = (const float4*)(C + (size_t)n * NC + base);
    float4 q0 = qp[0], q1 = qp[1];
    float qv[8] = {q0.x,q0.y,q0.z,q0.w,q1.x,q1.y,q1.z,q1.w};
    float we[8];
    #pragma unroll
    for (int j = 0; j < 8; j++) we[j] = Wel[base + j];

    float t = 0.f;
    #pragma unroll
    for (int j = 0; j < 8; j++) t = fmaf(qv[j], we[j], t);
    #pragma unroll
    for (int m = 1; m < 16; m <<= 1) t += __shfl_xor(t, m, 64);
    float qWe = t;

    float mrun = -1e30f, msum = 0.f, cattr = 0.f;
    float acc[8] = {0.f,0.f,0.f,0.f,0.f,0.f,0.f,0.f};
    int p0 = indptr[n], p1 = indptr[n + 1];

    auto consume = [&](uint4 ku, uint4 vu, float at) {
        union { uint4 u; u16 h[8]; } kr, vr;
        kr.u = ku; vr.u = vu;
        float d = 0.f;
        #pragma unroll
        for (int j = 0; j < 8; j++) d = fmaf(qv[j], h2f(kr.h[j]), d);
        #pragma unroll
        for (int m = 1; m < 16; m <<= 1) d += __shfl_xor(d, m, 64);
        float logit = (d + at * qWe) * SCALE;
        float mnew = fmaxf(mrun, logit);
        float r = __expf(mrun - mnew);
        float a = __expf(logit - mnew);
        msum  = msum  * r + a;
        cattr = cattr * r + a * at;
        #pragma unroll
        for (int j = 0; j < 8; j++) acc[j] = acc[j] * r + a * h2f(vr.h[j]);
        mrun = mnew;
    };

    uint4 ka = {0,0,0,0}, va = {0,0,0,0}, kb = {0,0,0,0}, vb = {0,0,0,0};
    float ata = 0.f, atb = 0.f;
    if (p0 < p1) {
        int s = ssrc[p0]; ata = sattr[p0];
        ka = *(const uint4*)(KV + (size_t)s * 4096 + 1024 + base);
        va = *(const uint4*)(KV + (size_t)s * 4096 + 1536 + base);
    }
    if (p0 + 1 < p1) {
        int s = ssrc[p0 + 1]; atb = sattr[p0 + 1];
        kb = *(const uint4*)(KV + (size_t)s * 4096 + 1024 + base);
        vb = *(const uint4*)(KV + (size_t)s * 4096 + 1536 + base);
    }
    int p = p0;
    for (; p + 1 < p1; p += 2) {
        uint4 kc = ka, vc = va; float atc = ata;
        if (p + 2 < p1) {
            int s = ssrc[p + 2]; ata = sattr[p + 2];
            ka = *(const uint4*)(KV + (size_t)s * 4096 + 1024 + base);
            va = *(const uint4*)(KV + (size_t)s * 4096 + 1536 + base);
        }
        consume(kc, vc, atc);
        kc = kb; vc = vb; atc = atb;
        if (p + 3 < p1) {
            int s = ssrc[p + 3]; atb = sattr[p + 3];
            kb = *(const uint4*)(KV + (size_t)s * 4096 + 1024 + base);
            vb = *(const uint4*)(KV + (size_t)s * 4096 + 1536 + base);
        }
        consume(kc, vc, atc);
    }
    if (p < p1) consume(ka, va, ata);

    float inv = 1.f / (msum + 1e-16f);
    float* op = C + (size_t)n * NC + 1536 + base;
    float4 o0 = *(float4*)op, o1 = *(float4*)(op + 4);
    float ov[8] = {o0.x,o0.y,o0.z,o0.w,o1.x,o1.y,o1.z,o1.w};
    #pragma unroll
    for (int j = 0; j < 8; j++) ov[j] += (acc[j] + cattr * we[j]) * inv;
    *(float4*)op       = make_float4(ov[0], ov[1], ov[2], ov[3]);
    *(float4*)(op + 4) = make_float4(ov[4], ov[5], ov[6], ov[7]);
}

// ---------------- GraphNorm ----------------
__global__ void colstat_kernel(const float* __restrict__ C,
                               float* __restrict__ cs, float* __restrict__ cq) {
    int c = threadIdx.x; // 0..255
    int r0 = blockIdx.x * 125;
    float s0 = 0, s1 = 0, q0 = 0, q1 = 0;
    for (int r = r0; r < r0 + 125; ++r) {
        float v0 = C[(size_t)r * NC + 1536 + c];
        float v1 = C[(size_t)r * NC + 1536 + c + 256];
        s0 += v0; q0 += v0 * v0;
        s1 += v1; q1 += v1 * v1;
    }
    atomicAdd(&cs[c], s0);       atomicAdd(&cq[c], q0);
    atomicAdd(&cs[c + 256], s1); atomicAdd(&cq[c + 256], q1);
}

__global__ void coef_kernel(const float* __restrict__ cs, const float* __restrict__ cq,
                            const float* __restrict__ gnw, const float* __restrict__ gnb,
                            const float* __restrict__ gnm,
                            float* __restrict__ Aa, float* __restrict__ Bb) {
    int c = blockIdx.x * 256 + threadIdx.x;
    if (c >= DD) return;
    float mean = cs[c] * (1.f / NN);
    float ex2  = cq[c] * (1.f / NN);
    float ms = gnm[c];
    float var = ex2 - (2.f * ms - ms * ms) * mean * mean;
    float A = gnw[c] * rsqrtf(var + 1e-5f);
    Aa[c] = A;
    Bb[c] = gnb[c] - A * ms * mean;
}

// norm + relu + write fp16 into A2 for the next GEMM / gram
__global__ void normrelu_kernel(const float* __restrict__ C, const float* __restrict__ Aa,
                                const float* __restrict__ Bb, u16* __restrict__ A2) {
    for (size_t idx = (size_t)blockIdx.x * 256 + threadIdx.x; idx < (size_t)NN * 512;
         idx += (size_t)2048 * 256) {
        int r = (int)(idx >> 9), c = (int)(idx & 511);
        float v = fmaxf(fmaf(Aa[c], C[(size_t)r * NC + 1536 + c], Bb[c]), 0.f);
        A2[(size_t)r * K2 + c] = f2h(v);
    }
}

// ---------------- gram via MFMA (fp16) ----------------
__global__ __launch_bounds__(256) void gram_part_kernel(const u16* __restrict__ A2,
                                                        float* __restrict__ part) {
    __shared__ u16 LA[128][40], LB[128][40];   // [col][node], 80B rows: conflict-free
    int b = blockIdx.x;
    int p = b >> 5, z = b & (GZ - 1);
    int ti, tj; tile_pair(p, ti, tj);
    int i0c = ti * 128, j0c = tj * 128;
    int st0 = (z * 316) / GZ, st1 = ((z + 1) * 316) / GZ;

    int t = threadIdx.x;
    int c = t & 127, nb = t >> 7;              // staging: col c, node-halves nb
    int wave = t >> 6, lane = t & 63;
    int wr = wave >> 1, wc = wave & 1;
    int frow = lane & 15, fk = (lane >> 4) * 8, rq = lane >> 4;

    f32x4 acc[4][4];
    #pragma unroll
    for (int m = 0; m < 4; ++m)
        #pragma unroll
        for (int n = 0; n < 4; ++n) acc[m][n] = (f32x4){0.f, 0.f, 0.f, 0.f};

    for (int st = st0; st < st1; ++st) {
        int node0 = st * 32 + nb * 16;
        uint4 bufA4[2], bufB4[2];
        u16* ba = (u16*)bufA4; u16* bb = (u16*)bufB4;
        #pragma unroll
        for (int i = 0; i < 16; i++) {
            const u16* rp = A2 + (size_t)(node0 + i) * K2;
            ba[i] = rp[i0c + c];
            bb[i] = rp[j0c + c];
        }
        __syncthreads();
        *(uint4*)&LA[c][nb * 16]     = bufA4[0];
        *(uint4*)&LA[c][nb * 16 + 8] = bufA4[1];
        *(uint4*)&LB[c][nb * 16]     = bufB4[0];
        *(uint4*)&LB[c][nb * 16 + 8] = bufB4[1];
        __syncthreads();
        f16x8 af[4], bfr[4];
        #pragma unroll
        for (int m = 0; m < 4; ++m)
            af[m] = *reinterpret_cast<const f16x8*>(&LA[wr * 64 + m * 16 + frow][fk]);
        #pragma unroll
        for (int n = 0; n < 4; ++n)
            bfr[n] = *reinterpret_cast<const f16x8*>(&LB[wc * 64 + n * 16 + frow][fk]);
        #pragma unroll
        for (int m = 0; m < 4; ++m)
            #pragma unroll
            for (int n = 0; n < 4; ++n)
                acc[m][n] = __builtin_amdgcn_mfma_f32_16x16x32_f16(af[m], bfr[n], acc[m][n], 0, 0, 0);
    }

    float* pp = part + ((size_t)b << 14);      // b = p*GZ+z
    #pragma unroll
    for (int m = 0; m < 4; ++m) {
        int li0 = wr * 64 + m * 16 + rq * 4;
        #pragma unroll
        for (int n = 0; n < 4; ++n) {
            int lj = wc * 64 + n * 16 + frow;
            #pragma unroll
            for (int r = 0; r < 4; ++r)
                pp[(li0 + r) * 128 + lj] = acc[m][n][r];
        }
    }
}

// reduce GZ partials per cell -> xt, fused per-block min/max partials
__global__ __launch_bounds__(256) void gram_reduce_kernel(const float* __restrict__ part,
                                                          float* __restrict__ xt,
                                                          float* __restrict__ pmn,
                                                          float* __restrict__ pmx) {
    __shared__ float smn[256], smx[256];
    int tid = threadIdx.x;
    int g = blockIdx.x * 1024 + tid * 4;       // 160 blocks * 1024 = 163840 cells
    int p = g >> 14, idx = g & 16383;
    const float* bp = part + ((size_t)p * GZ << 14) + idx;
    float4 s = make_float4(0.f, 0.f, 0.f, 0.f);
    #pragma unroll
    for (int z = 0; z < GZ; ++z) {
        float4 v = *(const float4*)(bp + (size_t)z * 16384);
        s.x += v.x; s.y += v.y; s.z += v.z; s.w += v.w;
    }
    int ti, tj; tile_pair(p, ti, tj);
    int li = idx >> 7, lj = idx & 127;
    *(float4*)&xt[(size_t)(ti * 128 + li) * DD + tj * 128 + lj] = s;
    float mn = fminf(fminf(s.x, s.y), fminf(s.z, s.w));
    float mx = fmaxf(fmaxf(s.x, s.y), fmaxf(s.z, s.w));
    smn[tid] = mn; smx[tid] = mx;
    __syncthreads();
    for (int st = 128; st > 0; st >>= 1) {
        if (tid < st) {
            smn[tid] = fminf(smn[tid], smn[tid + st]);
            smx[tid] = fmaxf(smx[tid], smx[tid + st]);
        }
        __syncthreads();
    }
    if (tid == 0) { pmn[blockIdx.x] = smn[0]; pmx[blockIdx.x] = smx[0]; }
}

__global__ void minmax2_kernel(const float* __restrict__ pmn, const float* __restrict__ pmx,
                               float* __restrict__ mm) {
    __shared__ float smn[256], smx[256];
    int tid = threadIdx.x;
    smn[tid] = (tid < 160) ? pmn[tid] : 1e30f;
    smx[tid] = (tid < 160) ? pmx[tid] : -1e30f;
    __syncthreads();
    for (int s = 128; s > 0; s >>= 1) {
        if (tid < s) { smn[tid] = fminf(smn[tid], smn[tid + s]); smx[tid] = fmaxf(smx[tid], smx[tid + s]); }
        __syncthreads();
    }
    if (tid == 0) { mm[0] = smn[0]; mm[1] = smx[0]; }
}

__global__ void final_kernel(const float* __restrict__ xt, const float* __restrict__ mm,
                             float* __restrict__ outp) {
    int idx = blockIdx.x * 256 + threadIdx.x;
    if (idx >= 262144) return;
    int i = idx >> 9, j = idx & 511;
    if (j <= i) return;
    float mn = mm[0], mx = mm[1];
    float v = (xt[idx] - mn) / (mx - mn + 1e-8f);
    int p = i * 511 - (i * (i - 1)) / 2 + (j - i - 1);
    outp[p] = v;
}

// ---------------- launch ----------------
extern "C" void kernel_launch(void* const* d_in, const int* in_sizes, int n_in,
                              void* d_out, int out_size, void* d_ws, size_t ws_size,
                              hipStream_t stream) {
    const float* x     = (const float*)d_in[0];
    const int*   ei    = (const int*)d_in[1];
    const float* eattr = (const float*)d_in[2];
    const float* Wq = (const float*)d_in[3];  const float* bq = (const float*)d_in[4];
    const float* Wk = (const float*)d_in[5];  const float* bk = (const float*)d_in[6];
    const float* Wv = (const float*)d_in[7];  const float* bv = (const float*)d_in[8];
    const float* We = (const float*)d_in[9];
    const float* Ws = (const float*)d_in[10]; const float* bs = (const float*)d_in[11];
    const float* gnw = (const float*)d_in[12];
    const float* gnb = (const float*)d_in[13];
    const float* gnm = (const float*)d_in[14];

    char*  wsb = (char*)d_ws;
    float* C    = (float*)(wsb + B_C);
    float* xt   = (float*)(wsb + B_XT);
    float* sm   = (float*)(wsb + B_SM);
    u16*   A2   = (u16*)(wsb + B_A2);
    u16*   B2T  = (u16*)(wsb + B_B2T);
    int*   wsI  = (int*)(wsb + B_INT);

    const int* src = ei;
    const int* dst = ei + NE;

    // conversions (once per call)
    convert_x_kernel<<<(MPAD * 512) / 256, 256, 0, stream>>>(x, A2);
    convert_w_kernel<<<dim3(8, 8, 8), dim3(64, 4), 0, stream>>>(Wq, Wk, Wv, Ws, B2T);
    convert_b_kernel<<<16, 256, 0, stream>>>(bq, bk, bv, bs, sm + SM_BIAS);

    // CSR by dst
    hipMemsetAsync(wsI + I_CNT, 0, NN * sizeof(int), stream);
    hist_kernel<<<(NE + 255) / 256, 256, 0, stream>>>(dst, wsI + I_CNT);
    scan_kernel<<<1, 1024, 0, stream>>>(wsI + I_CNT, wsI + I_INDPTR, wsI + I_CUR);
    scatter_kernel<<<(NE + 255) / 256, 256, 0, stream>>>(src, dst, eattr, wsI + I_CUR,
                                                         wsI + I_SSRC, (float*)(wsI + I_SATTR));

    for (int l = 0; l < NL; ++l) {
        gemm_mfma<<<1264, 256, 0, stream>>>(A2, B2T + (size_t)l * NC * K2,
                                            sm + SM_BIAS + (size_t)l * NC, C);

        agg_kernel<<<2500, 256, 0, stream>>>(C, We + (size_t)l * DD,
                                             wsI + I_INDPTR, wsI + I_SSRC,
                                             (const float*)(wsI + I_SATTR));

        hipMemsetAsync(sm + SM_CS, 0, 1024 * sizeof(float), stream);
        colstat_kernel<<<80, 256, 0, stream>>>(C, sm + SM_CS, sm + SM_CQ);
        coef_kernel<<<2, 256, 0, stream>>>(sm + SM_CS, sm + SM_CQ,
                                           gnw + (size_t)l * DD, gnb + (size_t)l * DD,
                                           gnm + (size_t)l * DD, sm + SM_CA, sm + SM_CB);
        normrelu_kernel<<<2048, 256, 0, stream>>>(C, sm + SM_CA, sm + SM_CB, A2);
    }

    // gram: partials (alias dead C buffer) -> reduce(+minmax) -> final
    float* part = C;
    gram_part_kernel<<<10 * GZ, 256, 0, stream>>>(A2, part);
    gram_reduce_kernel<<<160, 256, 0, stream>>>(part, xt, sm + SM_PMN, sm + SM_PMX);
    minmax2_kernel<<<1, 256, 0, stream>>>(sm + SM_PMN, sm + SM_PMX, sm + SM_MM);
    final_kernel<<<1024, 256, 0, stream>>>(xt, sm + SM_MM, (float*)d_out);
}

// Round 13
// 332.869 us; speedup vs baseline: 1.1216x; 1.0310x over previous
//
#include <hip/hip_runtime.h>
#include <math.h>
#include <stdint.h>

typedef unsigned short u16;
typedef __attribute__((ext_vector_type(8))) _Float16 f16x8;
typedef __attribute__((ext_vector_type(4))) float f32x4;

constexpr int NN = 10000;      // nodes
constexpr int NE = 160000;     // edges
constexpr int DD = 512;        // = H*C
constexpr int NL = 2;
constexpr int MPAD = 10112;    // 79*128
constexpr int K2 = 512;        // plain fp16 GEMM
constexpr int NC = 2048;       // C row stride (q f32 | kv fp16 alias | out f32)
constexpr int GZ = 32;         // gram K-chunks
constexpr int NKT = K2 / 32;   // 16 K-steps (BK=32, proven)
constexpr float SCALE = 0.08838834764831845f; // 1/sqrt(128)

// ---------------- workspace layout (byte offsets) ----------------
// C row (8192B): [0,2048)=q f32 | u16 idx [1024,2048) = k,v fp16 | f32 [1536,2048)=out
constexpr size_t B_C   = 0;                                   // [10016][2048] f32 (gram partials alias)
constexpr size_t B_XT  = (size_t)10016 * NC * 4;              // 82,051,072
constexpr size_t B_SM  = B_XT + (size_t)262144 * 4;           // small float block
constexpr size_t B_A2  = B_SM + 32768;                        // [10112][512] f16
constexpr size_t B_B2T = B_A2 + (size_t)MPAD * K2 * 2;        // [2][2048][512] f16
constexpr size_t B_INT = B_B2T + (size_t)2 * NC * K2 * 2;     // int region
// small-region float offsets
constexpr size_t SM_CS = 0, SM_CQ = 512, SM_CA = 1024, SM_CB = 1536;
constexpr size_t SM_PMN = 2048, SM_PMX = 2304, SM_MM = 2560, SM_BIAS = 2688; // bias 2*2048
// int sub-offsets
constexpr size_t I_INDPTR = 0;        // NN+1
constexpr size_t I_CNT    = 10016;    // NN
constexpr size_t I_CUR    = 20032;    // NN
constexpr size_t I_SSRC   = 30048;    // NE
constexpr size_t I_SATTR  = 190048;   // NE floats

// ---------------- helpers ----------------
__device__ __forceinline__ u16 f2h(float v) {
    _Float16 h = (_Float16)v;
    union { _Float16 h; u16 u; } x; x.h = h;
    return x.u;
}
__device__ __forceinline__ float h2f(u16 b) {
    union { u16 u; _Float16 h; } y; y.u = b;
    return (float)y.h;
}
__device__ __forceinline__ void gload16(const u16* g, u16* l) {
    __builtin_amdgcn_global_load_lds(
        (const __attribute__((address_space(1))) void*)g,
        (__attribute__((address_space(3))) void*)l, 16, 0, 0);
}
__device__ __forceinline__ void tile_pair(int p, int& ti, int& tj) {
    ti = (p < 4) ? 0 : (p < 7) ? 1 : (p < 9) ? 2 : 3;
    tj = p - ((ti == 0) ? 0 : (ti == 1) ? 3 : (ti == 2) ? 5 : 6);
}

// ---------------- CSR build ----------------
__global__ void hist_kernel(const int* __restrict__ dst, int* __restrict__ cnt) {
    int e = blockIdx.x * 256 + threadIdx.x;
    if (e < NE) atomicAdd(&cnt[dst[e]], 1);
}

__global__ void scan_kernel(const int* __restrict__ cnt, int* __restrict__ indptr,
                            int* __restrict__ cur) {
    __shared__ int sh[1024];
    int tid = threadIdx.x;
    int carry = 0;
    for (int base = 0; base < NN; base += 1024) {
        int idx = base + tid;
        int v = (idx < NN) ? cnt[idx] : 0;
        sh[tid] = v;
        __syncthreads();
        #pragma unroll
        for (int off = 1; off < 1024; off <<= 1) {
            int t = (tid >= off) ? sh[tid - off] : 0;
            __syncthreads();
            sh[tid] += t;
            __syncthreads();
        }
        int incl = sh[tid];
        int excl = incl - v;
        if (idx < NN) { indptr[idx] = carry + excl; cur[idx] = carry + excl; }
        int total = sh[1023];
        __syncthreads();
        carry += total;
    }
    if (tid == 0) indptr[NN] = carry;
}

__global__ void scatter_kernel(const int* __restrict__ src, const int* __restrict__ dst,
                               const float* __restrict__ eattr, int* __restrict__ cur,
                               int* __restrict__ ssrc, float* __restrict__ sattr) {
    int e = blockIdx.x * 256 + threadIdx.x;
    if (e < NE) {
        int d = dst[e];
        int p = atomicAdd(&cur[d], 1);
        ssrc[p]  = src[e];
        sattr[p] = eattr[e];
    }
}

// ---------------- conversions ----------------
__global__ void convert_x_kernel(const float* __restrict__ x, u16* __restrict__ A2) {
    size_t idx = (size_t)blockIdx.x * 256 + threadIdx.x;  // over MPAD*512
    if (idx >= (size_t)MPAD * 512) return;
    int r = (int)(idx >> 9), c = (int)(idx & 511);
    float v = (r < NN) ? x[(size_t)r * 512 + c] : 0.f;
    A2[(size_t)r * K2 + c] = f2h(v);
}

// grid (8,8,8): (ktile, ntile, l*4+mat); block (64,4)
__global__ void convert_w_kernel(const float* __restrict__ Wq, const float* __restrict__ Wk,
                                 const float* __restrict__ Wv, const float* __restrict__ Ws,
                                 u16* __restrict__ B2T) {
    __shared__ float t[64][65];
    int bz = blockIdx.z; int l = bz >> 2, m = bz & 3;
    const float* W = (m == 0 ? Wq : m == 1 ? Wk : m == 2 ? Wv : Ws) + (size_t)l * 512 * 512;
    int k0 = blockIdx.x * 64, n0 = blockIdx.y * 64;
    int tx = threadIdx.x, ty = threadIdx.y;
    #pragma unroll
    for (int i = 0; i < 16; i++) {
        int kk = ty + 4 * i;
        t[kk][tx] = W[(size_t)(k0 + kk) * 512 + n0 + tx];
    }
    __syncthreads();
    u16* B = B2T + (size_t)l * NC * K2;
    #pragma unroll
    for (int i = 0; i < 16; i++) {
        int nn = ty + 4 * i;
        B[(size_t)(m * 512 + n0 + nn) * K2 + k0 + tx] = f2h(t[tx][nn]);
    }
}

__global__ void convert_b_kernel(const float* __restrict__ bq, const float* __restrict__ bk,
                                 const float* __restrict__ bv, const float* __restrict__ bs,
                                 float* __restrict__ biascat) {
    int idx = blockIdx.x * 256 + threadIdx.x;  // 2*2048
    if (idx >= 2 * NC) return;
    int l = idx >> 11, c = idx & 2047;
    int m = c >> 9, j = c & 511;
    const float* b = (m == 0 ? bq : m == 1 ? bk : m == 2 ? bv : bs);
    biascat[idx] = b[l * 512 + j];
}

// ---------------- MFMA GEMM: [q|k|v|s] = A2[MPAD][512] @ B2T^T + bias ----------------
// Round-10 structure; XCD-aware M-panel decomposition: each XCD owns mb ≡ xcd (mod 8)
// and sweeps all 16 N-blocks -> per-XCD L2 set = A panel (1.25MB) + full B (2MB).
__global__ __launch_bounds__(256) void gemm_mfma(
    const u16* __restrict__ A2, const u16* __restrict__ B2T,
    const float* __restrict__ biasc, float* __restrict__ C)
{
    __shared__ u16 As[4096];  // [128][32]
    __shared__ u16 Bs[4096];  // [128 cols][32 k]
    int tid = threadIdx.x;
    int wave = tid >> 6, lane = tid & 63;
    int wr = wave >> 1, wc = wave & 1;

    int bid = blockIdx.x;                      // grid 1280
    int xcd = bid & 7;
    int j = bid >> 3;                          // 0..159
    int mb = (j >> 4) * 8 + xcd;               // M-block owned by this XCD
    int nb = j & 15;                           // N-block, fastest-varying per XCD
    if (mb >= 79) return;
    int row0 = mb * 128, col0 = nb * 128;
    int mtype = nb >> 2;                       // 0=q,1=k,2=v,3=s (block-uniform)

    int ar0 = tid >> 2;                // staging row within tile
    int ac0 = (tid & 3) * 8;           // staging k offset (elements)
    const u16* gA = A2  + (size_t)(row0 + ar0) * K2 + ac0;
    const u16* gB = B2T + (size_t)(col0 + ar0) * K2 + ac0;
    u16* lA = &As[wave * 512];
    u16* lB = &Bs[wave * 512];

    f32x4 acc[4][4];
    #pragma unroll
    for (int m = 0; m < 4; ++m)
        #pragma unroll
        for (int n = 0; n < 4; ++n) acc[m][n] = (f32x4){0.f, 0.f, 0.f, 0.f};

    int frow = lane & 15, fk = (lane >> 4) * 8;

    for (int kt = 0; kt < NKT; ++kt) {
        gload16(gA,             lA);
        gload16(gA + 64 * K2,   lA + 2048);
        gload16(gB,             lB);
        gload16(gB + 64 * K2,   lB + 2048);
        gA += 32; gB += 32;
        __syncthreads();
        f16x8 af[4], bfr[4];
        #pragma unroll
        for (int m = 0; m < 4; ++m)
            af[m] = *reinterpret_cast<const f16x8*>(&As[(wr * 64 + m * 16 + frow) * 32 + fk]);
        #pragma unroll
        for (int n = 0; n < 4; ++n)
            bfr[n] = *reinterpret_cast<const f16x8*>(&Bs[(wc * 64 + n * 16 + frow) * 32 + fk]);
        #pragma unroll
        for (int m = 0; m < 4; ++m)
            #pragma unroll
            for (int n = 0; n < 4; ++n)
                acc[m][n] = __builtin_amdgcn_mfma_f32_16x16x32_f16(af[m], bfr[n], acc[m][n], 0, 0, 0);
        __syncthreads();
    }

    u16* KV = (u16*)C;   // fp16 k/v live at u16 index r*4096 + 512 + gc  (gc in [512,1536))
    int rq = lane >> 4;
    #pragma unroll
    for (int n = 0; n < 4; ++n) {
        int gc = col0 + wc * 64 + n * 16 + frow;
        float bv = biasc[gc];
        #pragma unroll
        for (int m = 0; m < 4; ++m) {
            int gr0 = row0 + wr * 64 + m * 16 + rq * 4;
            #pragma unroll
            for (int r = 0; r < 4; ++r) {
                int gr = gr0 + r;
                if (gr < NN) {
                    float val = acc[m][n][r] + bv;
                    if (mtype == 0 || mtype == 3) C[(size_t)gr * NC + gc] = val;
                    else                          KV[(size_t)gr * 4096 + 512 + gc] = f2h(val);
                }
            }
        }
    }
}

// ---------------- per-node attention aggregate (online softmax, 2-deep prefetch) ----------------
__global__ __launch_bounds__(256) void agg_kernel(
    float* __restrict__ C, const float* __restrict__ Wel,
    const int* __restrict__ indptr, const int* __restrict__ ssrc,
    const float* __restrict__ sattr)
{
    int wid  = threadIdx.x >> 6;
    int lane = threadIdx.x & 63;
    int n = blockIdx.x * 4 + wid;
    if (n >= NN) return;
    int base = lane * 8;
    const u16* KV = (const u16*)C;

    const float4* qp = (const float4*)(C + (size_t)n * NC + base);
    float4 q0 = qp[0], q1 = qp[1];
    float qv[8] = {q0.x,q0.y,q0.z,q0.w,q1.x,q1.y,q1.z,q1.w};
    float we[8];
    #pragma unroll
    for (int j = 0; j < 8; j++) we[j] = Wel[base + j];

    float t = 0.f;
    #pragma unroll
    for (int j = 0; j < 8; j++) t = fmaf(qv[j], we[j], t);
    #pragma unroll
    for (int m = 1; m < 16; m <<= 1) t += __shfl_xor(t, m, 64);
    float qWe = t;

    float mrun = -1e30f, msum = 0.f, cattr = 0.f;
    float acc[8] = {0.f,0.f,0.f,0.f,0.f,0.f,0.f,0.f};
    int p0 = indptr[n], p1 = indptr[n + 1];

    auto consume = [&](uint4 ku, uint4 vu, float at) {
        union { uint4 u; u16 h[8]; } kr, vr;
        kr.u = ku; vr.u = vu;
        float d = 0.f;
        #pragma unroll
        for (int j = 0; j < 8; j++) d = fmaf(qv[j], h2f(kr.h[j]), d);
        #pragma unroll
        for (int m = 1; m < 16; m <<= 1) d += __shfl_xor(d, m, 64);
        float logit = (d + at * qWe) * SCALE;
        float mnew = fmaxf(mrun, logit);
        float r = __expf(mrun - mnew);
        float a = __expf(logit - mnew);
        msum  = msum  * r + a;
        cattr = cattr * r + a * at;
        #pragma unroll
        for (int j = 0; j < 8; j++) acc[j] = acc[j] * r + a * h2f(vr.h[j]);
        mrun = mnew;
    };

    uint4 ka = {0,0,0,0}, va = {0,0,0,0}, kb = {0,0,0,0}, vb = {0,0,0,0};
    float ata = 0.f, atb = 0.f;
    if (p0 < p1) {
        int s = ssrc[p0]; ata = sattr[p0];
        ka = *(const uint4*)(KV + (size_t)s * 4096 + 1024 + base);
        va = *(const uint4*)(KV + (size_t)s * 4096 + 1536 + base);
    }
    if (p0 + 1 < p1) {
        int s = ssrc[p0 + 1]; atb = sattr[p0 + 1];
        kb = *(const uint4*)(KV + (size_t)s * 4096 + 1024 + base);
        vb = *(const uint4*)(KV + (size_t)s * 4096 + 1536 + base);
    }
    int p = p0;
    for (; p + 1 < p1; p += 2) {
        uint4 kc = ka, vc = va; float atc = ata;
        if (p + 2 < p1) {
            int s = ssrc[p + 2]; ata = sattr[p + 2];
            ka = *(const uint4*)(KV + (size_t)s * 4096 + 1024 + base);
            va = *(const uint4*)(KV + (size_t)s * 4096 + 1536 + base);
        }
        consume(kc, vc, atc);
        kc = kb; vc = vb; atc = atb;
        if (p + 3 < p1) {
            int s = ssrc[p + 3]; atb = sattr[p + 3];
            kb = *(const uint4*)(KV + (size_t)s * 4096 + 1024 + base);
            vb = *(const uint4*)(KV + (size_t)s * 4096 + 1536 + base);
        }
        consume(kc, vc, atc);
    }
    if (p < p1) consume(ka, va, ata);

    float inv = 1.f / (msum + 1e-16f);
    float* op = C + (size_t)n * NC + 1536 + base;
    float4 o0 = *(float4*)op, o1 = *(float4*)(op + 4);
    float ov[8] = {o0.x,o0.y,o0.z,o0.w,o1.x,o1.y,o1.z,o1.w};
    #pragma unroll
    for (int j = 0; j < 8; j++) ov[j] += (acc[j] + cattr * we[j]) * inv;
    *(float4*)op       = make_float4(ov[0], ov[1], ov[2], ov[3]);
    *(float4*)(op + 4) = make_float4(ov[4], ov[5], ov[6], ov[7]);
}

// ---------------- GraphNorm ----------------
__global__ void colstat_kernel(const float* __restrict__ C,
                               float* __restrict__ cs, float* __restrict__ cq) {
    int c = threadIdx.x; // 0..255
    int r0 = blockIdx.x * 125;
    float s0 = 0, s1 = 0, q0 = 0, q1 = 0;
    for (int r = r0; r < r0 + 125; ++r) {
        float v0 = C[(size_t)r * NC + 1536 + c];
        float v1 = C[(size_t)r * NC + 1536 + c + 256];
        s0 += v0; q0 += v0 * v0;
        s1 += v1; q1 += v1 * v1;
    }
    atomicAdd(&cs[c], s0);       atomicAdd(&cq[c], q0);
    atomicAdd(&cs[c + 256], s1); atomicAdd(&cq[c + 256], q1);
}

__global__ void coef_kernel(const float* __restrict__ cs, const float* __restrict__ cq,
                            const float* __restrict__ gnw, const float* __restrict__ gnb,
                            const float* __restrict__ gnm,
                            float* __restrict__ Aa, float* __restrict__ Bb) {
    int c = blockIdx.x * 256 + threadIdx.x;
    if (c >= DD) return;
    float mean = cs[c] * (1.f / NN);
    float ex2  = cq[c] * (1.f / NN);
    float ms = gnm[c];
    float var = ex2 - (2.f * ms - ms * ms) * mean * mean;
    float A = gnw[c] * rsqrtf(var + 1e-5f);
    Aa[c] = A;
    Bb[c] = gnb[c] - A * ms * mean;
}

// norm + relu + write fp16 into A2 for the next GEMM / gram
__global__ void normrelu_kernel(const float* __restrict__ C, const float* __restrict__ Aa,
                                const float* __restrict__ Bb, u16* __restrict__ A2) {
    for (size_t idx = (size_t)blockIdx.x * 256 + threadIdx.x; idx < (size_t)NN * 512;
         idx += (size_t)2048 * 256) {
        int r = (int)(idx >> 9), c = (int)(idx & 511);
        float v = fmaxf(fmaf(Aa[c], C[(size_t)r * NC + 1536 + c], Bb[c]), 0.f);
        A2[(size_t)r * K2 + c] = f2h(v);
    }
}

// ---------------- gram via MFMA (fp16) ----------------
__global__ __launch_bounds__(256) void gram_part_kernel(const u16* __restrict__ A2,
                                                        float* __restrict__ part) {
    __shared__ u16 LA[128][40], LB[128][40];   // [col][node], 80B rows: conflict-free
    int b = blockIdx.x;
    int p = b >> 5, z = b & (GZ - 1);
    int ti, tj; tile_pair(p, ti, tj);
    int i0c = ti * 128, j0c = tj * 128;
    int st0 = (z * 316) / GZ, st1 = ((z + 1) * 316) / GZ;

    int t = threadIdx.x;
    int c = t & 127, nb = t >> 7;              // staging: col c, node-halves nb
    int wave = t >> 6, lane = t & 63;
    int wr = wave >> 1, wc = wave & 1;
    int frow = lane & 15, fk = (lane >> 4) * 8, rq = lane >> 4;

    f32x4 acc[4][4];
    #pragma unroll
    for (int m = 0; m < 4; ++m)
        #pragma unroll
        for (int n = 0; n < 4; ++n) acc[m][n] = (f32x4){0.f, 0.f, 0.f, 0.f};

    for (int st = st0; st < st1; ++st) {
        int node0 = st * 32 + nb * 16;
        uint4 bufA4[2], bufB4[2];
        u16* ba = (u16*)bufA4; u16* bb = (u16*)bufB4;
        #pragma unroll
        for (int i = 0; i < 16; i++) {
            const u16* rp = A2 + (size_t)(node0 + i) * K2;
            ba[i] = rp[i0c + c];
            bb[i] = rp[j0c + c];
        }
        __syncthreads();
        *(uint4*)&LA[c][nb * 16]     = bufA4[0];
        *(uint4*)&LA[c][nb * 16 + 8] = bufA4[1];
        *(uint4*)&LB[c][nb * 16]     = bufB4[0];
        *(uint4*)&LB[c][nb * 16 + 8] = bufB4[1];
        __syncthreads();
        f16x8 af[4], bfr[4];
        #pragma unroll
        for (int m = 0; m < 4; ++m)
            af[m] = *reinterpret_cast<const f16x8*>(&LA[wr * 64 + m * 16 + frow][fk]);
        #pragma unroll
        for (int n = 0; n < 4; ++n)
            bfr[n] = *reinterpret_cast<const f16x8*>(&LB[wc * 64 + n * 16 + frow][fk]);
        #pragma unroll
        for (int m = 0; m < 4; ++m)
            #pragma unroll
            for (int n = 0; n < 4; ++n)
                acc[m][n] = __builtin_amdgcn_mfma_f32_16x16x32_f16(af[m], bfr[n], acc[m][n], 0, 0, 0);
    }

    float* pp = part + ((size_t)b << 14);      // b = p*GZ+z
    #pragma unroll
    for (int m = 0; m < 4; ++m) {
        int li0 = wr * 64 + m * 16 + rq * 4;
        #pragma unroll
        for (int n = 0; n < 4; ++n) {
            int lj = wc * 64 + n * 16 + frow;
            #pragma unroll
            for (int r = 0; r < 4; ++r)
                pp[(li0 + r) * 128 + lj] = acc[m][n][r];
        }
    }
}

// reduce GZ partials per cell -> xt, fused per-block min/max partials
__global__ __launch_bounds__(256) void gram_reduce_kernel(const float* __restrict__ part,
                                                          float* __restrict__ xt,
                                                          float* __restrict__ pmn,
                                                          float* __restrict__ pmx) {
    __shared__ float smn[256], smx[256];
    int tid = threadIdx.x;
    int g = blockIdx.x * 1024 + tid * 4;       // 160 blocks * 1024 = 163840 cells
    int p = g >> 14, idx = g & 16383;
    const float* bp = part + ((size_t)p * GZ << 14) + idx;
    float4 s = make_float4(0.f, 0.f, 0.f, 0.f);
    #pragma unroll
    for (int z = 0; z < GZ; ++z) {
        float4 v = *(const float4*)(bp + (size_t)z * 16384);
        s.x += v.x; s.y += v.y; s.z += v.z; s.w += v.w;
    }
    int ti, tj; tile_pair(p, ti, tj);
    int li = idx >> 7, lj = idx & 127;
    *(float4*)&xt[(size_t)(ti * 128 + li) * DD + tj * 128 + lj] = s;
    float mn = fminf(fminf(s.x, s.y), fminf(s.z, s.w));
    float mx = fmaxf(fmaxf(s.x, s.y), fmaxf(s.z, s.w));
    smn[tid] = mn; smx[tid] = mx;
    __syncthreads();
    for (int st = 128; st > 0; st >>= 1) {
        if (tid < st) {
            smn[tid] = fminf(smn[tid], smn[tid + st]);
            smx[tid] = fmaxf(smx[tid], smx[tid + st]);
        }
        __syncthreads();
    }
    if (tid == 0) { pmn[blockIdx.x] = smn[0]; pmx[blockIdx.x] = smx[0]; }
}

__global__ void minmax2_kernel(const float* __restrict__ pmn, const float* __restrict__ pmx,
                               float* __restrict__ mm) {
    __shared__ float smn[256], smx[256];
    int tid = threadIdx.x;
    smn[tid] = (tid < 160) ? pmn[tid] : 1e30f;
    smx[tid] = (tid < 160) ? pmx[tid] : -1e30f;
    __syncthreads();
    for (int s = 128; s > 0; s >>= 1) {
        if (tid < s) { smn[tid] = fminf(smn[tid], smn[tid + s]); smx[tid] = fmaxf(smx[tid], smx[tid + s]); }
        __syncthreads();
    }
    if (tid == 0) { mm[0] = smn[0]; mm[1] = smx[0]; }
}

__global__ void final_kernel(const float* __restrict__ xt, const float* __restrict__ mm,
                             float* __restrict__ outp) {
    int idx = blockIdx.x * 256 + threadIdx.x;
    if (idx >= 262144) return;
    int i = idx >> 9, j = idx & 511;
    if (j <= i) return;
    float mn = mm[0], mx = mm[1];
    float v = (xt[idx] - mn) / (mx - mn + 1e-8f);
    int p = i * 511 - (i * (i - 1)) / 2 + (j - i - 1);
    outp[p] = v;
}

// ---------------- launch ----------------
extern "C" void kernel_launch(void* const* d_in, const int* in_sizes, int n_in,
                              void* d_out, int out_size, void* d_ws, size_t ws_size,
                              hipStream_t stream) {
    const float* x     = (const float*)d_in[0];
    const int*   ei    = (const int*)d_in[1];
    const float* eattr = (const float*)d_in[2];
    const float* Wq = (const float*)d_in[3];  const float* bq = (const float*)d_in[4];
    const float* Wk = (const float*)d_in[5];  const float* bk = (const float*)d_in[6];
    const float* Wv = (const float*)d_in[7];  const float* bv = (const float*)d_in[8];
    const float* We = (const float*)d_in[9];
    const float* Ws = (const float*)d_in[10]; const float* bs = (const float*)d_in[11];
    const float* gnw = (const float*)d_in[12];
    const float* gnb = (const float*)d_in[13];
    const float* gnm = (const float*)d_in[14];

    char*  wsb = (char*)d_ws;
    float* C    = (float*)(wsb + B_C);
    float* xt   = (float*)(wsb + B_XT);
    float* sm   = (float*)(wsb + B_SM);
    u16*   A2   = (u16*)(wsb + B_A2);
    u16*   B2T  = (u16*)(wsb + B_B2T);
    int*   wsI  = (int*)(wsb + B_INT);

    const int* src = ei;
    const int* dst = ei + NE;

    // conversions (once per call)
    convert_x_kernel<<<(MPAD * 512) / 256, 256, 0, stream>>>(x, A2);
    convert_w_kernel<<<dim3(8, 8, 8), dim3(64, 4), 0, stream>>>(Wq, Wk, Wv, Ws, B2T);
    convert_b_kernel<<<16, 256, 0, stream>>>(bq, bk, bv, bs, sm + SM_BIAS);

    // CSR by dst
    hipMemsetAsync(wsI + I_CNT, 0, NN * sizeof(int), stream);
    hist_kernel<<<(NE + 255) / 256, 256, 0, stream>>>(dst, wsI + I_CNT);
    scan_kernel<<<1, 1024, 0, stream>>>(wsI + I_CNT, wsI + I_INDPTR, wsI + I_CUR);
    scatter_kernel<<<(NE + 255) / 256, 256, 0, stream>>>(src, dst, eattr, wsI + I_CUR,
                                                         wsI + I_SSRC, (float*)(wsI + I_SATTR));

    for (int l = 0; l < NL; ++l) {
        gemm_mfma<<<1280, 256, 0, stream>>>(A2, B2T + (size_t)l * NC * K2,
                                            sm + SM_BIAS + (size_t)l * NC, C);

        agg_kernel<<<2500, 256, 0, stream>>>(C, We + (size_t)l * DD,
                                             wsI + I_INDPTR, wsI + I_SSRC,
                                             (const float*)(wsI + I_SATTR));

        hipMemsetAsync(sm + SM_CS, 0, 1024 * sizeof(float), stream);
        colstat_kernel<<<80, 256, 0, stream>>>(C, sm + SM_CS, sm + SM_CQ);
        coef_kernel<<<2, 256, 0, stream>>>(sm + SM_CS, sm + SM_CQ,
                                           gnw + (size_t)l * DD, gnb + (size_t)l * DD,
                                           gnm + (size_t)l * DD, sm + SM_CA, sm + SM_CB);
        normrelu_kernel<<<2048, 256, 0, stream>>>(C, sm + SM_CA, sm + SM_CB, A2);
    }

    // gram: partials (alias dead C buffer) -> reduce(+minmax) -> final
    float* part = C;
    gram_part_kernel<<<10 * GZ, 256, 0, stream>>>(A2, part);
    gram_reduce_kernel<<<160, 256, 0, stream>>>(part, xt, sm + SM_PMN, sm + SM_PMX);
    minmax2_kernel<<<1, 256, 0, stream>>>(sm + SM_PMN, sm + SM_PMX, sm + SM_MM);
    final_kernel<<<1024, 256, 0, stream>>>(xt, sm + SM_MM, (float*)d_out);
}